// Round 7
// baseline (487.036 us; speedup 1.0000x reference)
//
#include <hip/hip_runtime.h>
#include <hip/hip_bf16.h>

#define NN 50000
#define NE 500000
#define F 128
#define K_IN 128
#define ED 64
#define C 2
#define NEG 0.2f
#define FLTMAX 3.402823466e38f

typedef __attribute__((ext_vector_type(8))) short short8;
typedef __attribute__((ext_vector_type(4))) float f32x4;

#define FMA4(acc, v, s) do { \
    acc[0] = fmaf((v)[0], (s), acc[0]); \
    acc[1] = fmaf((v)[1], (s), acc[1]); \
    acc[2] = fmaf((v)[2], (s), acc[2]); \
    acc[3] = fmaf((v)[3], (s), acc[3]); } while (0)

__device__ __forceinline__ short bf16r(float f) {
    unsigned u = __float_as_uint(f);
    unsigned r = (u + 0x7fffu + ((u >> 16) & 1u)) >> 16;
    return (short)r;
}

__device__ __forceinline__ short8 ldfrag(const float* base) {
    const float4* p = reinterpret_cast<const float4*>(base);
    float4 v0 = p[0], v1 = p[1];
    short8 r;
    r[0] = bf16r(v0.x); r[1] = bf16r(v0.y); r[2] = bf16r(v0.z); r[3] = bf16r(v0.w);
    r[4] = bf16r(v1.x); r[5] = bf16r(v1.y); r[6] = bf16r(v1.z); r[7] = bf16r(v1.w);
    return r;
}

// ---------------- projection via MFMA: xb = x @ W_l^T ----------------
__global__ __launch_bounds__(256) void proj_mfma(const float* __restrict__ x,
                                                 const float* __restrict__ W_l,
                                                 float* __restrict__ xb) {
    int lane = threadIdx.x & 63, wid = threadIdx.x >> 6;
    int grp = lane >> 4, col = lane & 15;
    int tile = blockIdx.x * 4 + wid;
    if (tile >= NN / 16) return;
    int n0 = tile * 16;

    f32x4 acc[8];
#pragma unroll
    for (int t = 0; t < 8; ++t) acc[t] = (f32x4){0.f, 0.f, 0.f, 0.f};

    const float* arow = x + (size_t)(n0 + col) * K_IN + grp * 8;
#pragma unroll
    for (int kt = 0; kt < 4; ++kt) {
        short8 a = ldfrag(arow + kt * 32);
#pragma unroll
        for (int t = 0; t < 8; ++t) {
            short8 b = ldfrag(W_l + (size_t)(t * 16 + col) * K_IN + kt * 32 + grp * 8);
            acc[t] = __builtin_amdgcn_mfma_f32_16x16x32_bf16(a, b, acc[t], 0, 0, 0);
        }
    }
#pragma unroll
    for (int j = 0; j < 4; ++j) {
        float* orow = xb + (size_t)(n0 + grp * 4 + j) * F + col;
#pragma unroll
        for (int t = 0; t < 8; ++t) orow[t * 16] = acc[t][j];
    }
}

// ---------------- CSR build ----------------
__global__ void hist_kernel(const int* __restrict__ ei, int* __restrict__ counts) {
    int e = blockIdx.x * blockDim.x + threadIdx.x;
    if (e < NE) atomicAdd(&counts[ei[NE + e]], 1);
}

__global__ __launch_bounds__(1024) void scan1_kernel(const int* __restrict__ counts,
                                                     int* __restrict__ offs,
                                                     int* __restrict__ bsum) {
    __shared__ int wsum[16];
    int i = blockIdx.x * 1024 + threadIdx.x;
    int lane = threadIdx.x & 63, w = threadIdx.x >> 6;
    int v = (i < NN) ? counts[i] : 0;
    int x = v;
#pragma unroll
    for (int off = 1; off < 64; off <<= 1) {
        int y = __shfl_up(x, off, 64);
        if (lane >= off) x += y;
    }
    if (lane == 63) wsum[w] = x;
    __syncthreads();
    if (w == 0 && lane < 16) {
        int t = wsum[lane];
#pragma unroll
        for (int off = 1; off < 16; off <<= 1) {
            int y = __shfl_up(t, off, 16);
            if (lane >= off) t += y;
        }
        wsum[lane] = t;
    }
    __syncthreads();
    int woff = (w == 0) ? 0 : wsum[w - 1];
    if (i < NN) offs[i] = woff + x - v;
    if (threadIdx.x == 1023) bsum[blockIdx.x] = woff + x;
}

__global__ void scan2_kernel(int* __restrict__ bsum, int nb) {
    int tid = threadIdx.x;
    int v = (tid < nb) ? bsum[tid] : 0;
    int x = v;
#pragma unroll
    for (int off = 1; off < 64; off <<= 1) {
        int y = __shfl_up(x, off, 64);
        if (tid >= off) x += y;
    }
    if (tid < nb) bsum[tid] = x - v;
}

__global__ __launch_bounds__(1024) void scan3_kernel(int* __restrict__ offs,
                                                     const int* __restrict__ bsum,
                                                     int* __restrict__ cursor) {
    int i = blockIdx.x * 1024 + threadIdx.x;
    if (i < NN) {
        int o = offs[i] + bsum[blockIdx.x];
        offs[i] = o;
        cursor[i] = o;
    }
    if (i == 0) offs[NN] = NE;
}

// perm2[p] = {edge, src}
__global__ void scatter_kernel(const int* __restrict__ ei, int* __restrict__ cursor,
                               int2* __restrict__ perm2) {
    int e = blockIdx.x * blockDim.x + threadIdx.x;
    if (e < NE) {
        int src = ei[e];
        int p = atomicAdd(&cursor[ei[NE + e]], 1);
        int2 v; v.x = e; v.y = src;
        perm2[p] = v;
    }
}

// ---------------- edge logits, ORIGINAL order, B-fragments in LDS ----------------
__global__ __launch_bounds__(256, 5) void edge_logits_mfma(
    const int* __restrict__ ei, const float* __restrict__ ea,
    const float* __restrict__ xb, const float* __restrict__ W_e,
    const float* __restrict__ cb, const float* __restrict__ att,
    const float* __restrict__ att_sc, const float* __restrict__ ebias,
    float* __restrict__ lgs) {
    __shared__ short8 Blds[16][64]; // [t*2+kt][lane] in fragment order, 16 KB
    int lane = threadIdx.x & 63, wid = threadIdx.x >> 6;
    int grp = lane >> 4, col = lane & 15;

    for (int fidx = threadIdx.x; fidx < 1024; fidx += 256) {
        int l = fidx & 63, kt = (fidx >> 6) & 1, t = fidx >> 7;
        int g2 = l >> 4, c2 = l & 15;
        Blds[t * 2 + kt][l] = ldfrag(W_e + (size_t)(t * 16 + c2) * ED + kt * 32 + g2 * 8);
    }

    float attv[8], cbe0[8], cbe1[8];
#pragma unroll
    for (int t = 0; t < 8; ++t) {
        int f = t * 16 + col;
        attv[t] = att[f];
        cbe0[t] = cb[f] + ebias[f * 2];
        cbe1[t] = cb[F + f] + ebias[f * 2 + 1];
    }
    float as0 = att_sc[0], as1 = att_sc[1];
    float2* lgs2 = reinterpret_cast<float2*>(lgs);
    __syncthreads();

    for (int tile = blockIdx.x * 4 + wid; tile < NE / 16; tile += gridDim.x * 4) {
        int e0 = tile * 16;
        int e_lin = e0 + col;
        int srcv = ei[e_lin];          // coalesced sequential
        int tgtv = ei[NE + e_lin];     // coalesced sequential
        const float* arow = ea + (size_t)e_lin * ED + grp * 8;  // sequential rows
        short8 a0 = ldfrag(arow);
        short8 a1 = ldfrag(arow + 32);
        f32x4 acc[8];
#pragma unroll
        for (int t = 0; t < 8; ++t) acc[t] = (f32x4){0.f, 0.f, 0.f, 0.f};
#pragma unroll
        for (int t = 0; t < 8; ++t) {
            acc[t] = __builtin_amdgcn_mfma_f32_16x16x32_bf16(a0, Blds[t * 2][lane], acc[t], 0, 0, 0);
            acc[t] = __builtin_amdgcn_mfma_f32_16x16x32_bf16(a1, Blds[t * 2 + 1][lane], acc[t], 0, 0, 0);
        }
#pragma unroll
        for (int j = 0; j < 4; ++j) {
            int idx = grp * 4 + j;
            int src = __shfl(srcv, idx, 16);
            int tgt = __shfl(tgtv, idx, 16);
            const float* xbs = xb + (size_t)src * F + col;
            const float* xbt = xb + (size_t)tgt * F + col;
            float q0 = 0.f, q1 = 0.f;
#pragma unroll
            for (int t = 0; t < 8; ++t) {
                float s = xbs[t * 16] + xbt[t * 16] + acc[t][j];
                float u0 = s + cbe0[t]; u0 = fmaxf(u0, NEG * u0);
                float u1 = s + cbe1[t]; u1 = fmaxf(u1, NEG * u1);
                q0 = fmaf(u0, attv[t], q0);
                q1 = fmaf(u1, attv[t], q1);
            }
#pragma unroll
            for (int off = 8; off; off >>= 1) {
                q0 += __shfl_xor(q0, off, 16);
                q1 += __shfl_xor(q1, off, 16);
            }
            if (col == 0) {
                float2 o; o.x = q0 * as0; o.y = q1 * as1;
                lgs2[e0 + idx] = o;   // original-order position
            }
        }
    }
}

// gather 4 edges/iter into float4 accumulators
__device__ __forceinline__ void gather4(int cdeg, int el, int sl, float e0v, float e1v,
                                        float inv0, float inv1,
                                        const float* __restrict__ ea,
                                        const float* __restrict__ xb, int lane,
                                        f32x4& h0q, f32x4& h1q, f32x4& g0, f32x4& g1) {
    int quad = lane >> 4, sub16 = lane & 15;
    int half = lane >> 5, sub32 = lane & 31;
    for (int jj = 0; jj < cdeg; jj += 4) {
        int idx = jj + quad;
        int cidx = min(idx, cdeg - 1);
        float w0 = (idx < cdeg) ? inv0 : 0.f;
        float w1 = (idx < cdeg) ? inv1 : 0.f;
        float a0q = __shfl(e0v, cidx, 64) * w0;
        float a1q = __shfl(e1v, cidx, 64) * w1;
        int eq = __shfl(el, cidx, 64);
        f32x4 ev = *reinterpret_cast<const f32x4*>(ea + (size_t)eq * ED + sub16 * 4);
        FMA4(h0q, ev, a0q); FMA4(h1q, ev, a1q);

        int idh = jj + half;
        int ch = min(idh, cdeg - 1);
        float b0 = (idh < cdeg) ? inv0 : 0.f;
        float b1 = (idh < cdeg) ? inv1 : 0.f;
        float aA0 = __shfl(e0v, ch, 64) * b0;
        float aA1 = __shfl(e1v, ch, 64) * b1;
        int sA = __shfl(sl, ch, 64);
        f32x4 xv = *reinterpret_cast<const f32x4*>(xb + (size_t)sA * F + sub32 * 4);
        FMA4(g0, xv, aA0); FMA4(g1, xv, aA1);

        int idh2 = jj + 2 + half;
        int ch2 = min(idh2, cdeg - 1);
        float c0 = (idh2 < cdeg) ? inv0 : 0.f;
        float c1 = (idh2 < cdeg) ? inv1 : 0.f;
        float aB0 = __shfl(e0v, ch2, 64) * c0;
        float aB1 = __shfl(e1v, ch2, 64) * c1;
        int sB = __shfl(sl, ch2, 64);
        f32x4 xv2 = *reinterpret_cast<const f32x4*>(xb + (size_t)sB * F + sub32 * 4);
        FMA4(g0, xv2, aB0); FMA4(g1, xv2, aB1);
    }
}

// ---------------- factored CSR aggregation (lgs gathered by edge id) ----------------
__global__ __launch_bounds__(512) void agg_fast(
    const int* __restrict__ offs, const int2* __restrict__ perm2,
    const float* __restrict__ ea, const float* __restrict__ xb,
    const float* __restrict__ ebias, const float* __restrict__ lgs,
    float* __restrict__ out, float* __restrict__ alpha_out,
    float* __restrict__ H) {
    int lane = threadIdx.x & 63;
    int node = blockIdx.x * 8 + (threadIdx.x >> 6);
    if (node >= NN) return;
    int beg = offs[node], end = offs[node + 1];
    int deg = end - beg;
    int half = lane >> 5, sub32 = lane & 31;
    float* orow = out + (size_t)node * (C * F);
    float* hrow = H + (size_t)node * (C * ED);

    if (deg == 0) {
        f32x4 z = (f32x4){0.f, 0.f, 0.f, 0.f};
        *reinterpret_cast<f32x4*>(orow + half * F + sub32 * 4) = z;
        if (lane < 32) *reinterpret_cast<f32x4*>(hrow + lane * 4) = z;
        return;
    }
    const float2* lgs2 = reinterpret_cast<const float2*>(lgs);
    float2* al2 = reinterpret_cast<float2*>(alpha_out);

    f32x4 h0q = (f32x4){0.f,0.f,0.f,0.f}, h1q = h0q, gA0 = h0q, gA1 = h0q;
    float s0, s1, inv0, inv1;

    if (deg <= 64) {
        int jl = beg + min(lane, deg - 1);
        int2 pe = perm2[jl];
        int el = pe.x, sl = pe.y;
        float2 lgl = lgs2[el];           // gather by edge id
        bool act = lane < deg;
        float l0 = act ? lgl.x : -FLTMAX;
        float l1 = act ? lgl.y : -FLTMAX;
        float m0 = l0, m1 = l1;
#pragma unroll
        for (int off = 32; off; off >>= 1) {
            m0 = fmaxf(m0, __shfl_xor(m0, off, 64));
            m1 = fmaxf(m1, __shfl_xor(m1, off, 64));
        }
        float e0v = act ? __expf(l0 - m0) : 0.f;
        float e1v = act ? __expf(l1 - m1) : 0.f;
        s0 = e0v; s1 = e1v;
#pragma unroll
        for (int off = 32; off; off >>= 1) {
            s0 += __shfl_xor(s0, off, 64);
            s1 += __shfl_xor(s1, off, 64);
        }
        inv0 = 1.f / (s0 + 1e-16f); inv1 = 1.f / (s1 + 1e-16f);
        if (act) { float2 av; av.x = e0v * inv0; av.y = e1v * inv1; al2[el] = av; }
        gather4(deg, el, sl, e0v, e1v, inv0, inv1, ea, xb, lane, h0q, h1q, gA0, gA1);
    } else {
        float m0 = -FLTMAX, m1 = -FLTMAX;
        for (int j = beg + lane; j < end; j += 64) {
            float2 lg = lgs2[perm2[j].x];
            m0 = fmaxf(m0, lg.x); m1 = fmaxf(m1, lg.y);
        }
#pragma unroll
        for (int off = 32; off; off >>= 1) {
            m0 = fmaxf(m0, __shfl_xor(m0, off, 64));
            m1 = fmaxf(m1, __shfl_xor(m1, off, 64));
        }
        s0 = 0.f; s1 = 0.f;
        for (int j = beg + lane; j < end; j += 64) {
            float2 lg = lgs2[perm2[j].x];
            s0 += __expf(lg.x - m0); s1 += __expf(lg.y - m1);
        }
#pragma unroll
        for (int off = 32; off; off >>= 1) {
            s0 += __shfl_xor(s0, off, 64);
            s1 += __shfl_xor(s1, off, 64);
        }
        inv0 = 1.f / (s0 + 1e-16f); inv1 = 1.f / (s1 + 1e-16f);
        for (int cb0 = beg; cb0 < end; cb0 += 64) {
            int cdeg = min(64, end - cb0);
            int jl = cb0 + min(lane, cdeg - 1);
            int2 pe = perm2[jl];
            int el = pe.x, sl = pe.y;
            float2 lgl = lgs2[el];
            bool act = lane < cdeg;
            float e0v = act ? __expf(lgl.x - m0) : 0.f;
            float e1v = act ? __expf(lgl.y - m1) : 0.f;
            if (act) { float2 av; av.x = e0v * inv0; av.y = e1v * inv1; al2[el] = av; }
            gather4(cdeg, el, sl, e0v, e1v, inv0, inv1, ea, xb, lane, h0q, h1q, gA0, gA1);
        }
    }

#pragma unroll
    for (int ccc = 0; ccc < 4; ++ccc) {
        h0q[ccc] += __shfl_xor(h0q[ccc], 16, 64);
        h0q[ccc] += __shfl_xor(h0q[ccc], 32, 64);
        h1q[ccc] += __shfl_xor(h1q[ccc], 16, 64);
        h1q[ccc] += __shfl_xor(h1q[ccc], 32, 64);
        gA0[ccc] += __shfl_xor(gA0[ccc], 32, 64);
        gA1[ccc] += __shfl_xor(gA1[ccc], 32, 64);
    }
    if (lane < 32) {
        f32x4 hv = (lane < 16) ? h0q : h1q;
        *reinterpret_cast<f32x4*>(hrow + ((lane >> 4) * ED) + (lane & 15) * 4) = hv;
    }
    f32x4 gsel = half ? gA1 : gA0;
    float sa = (half ? s1 * inv1 : s0 * inv0);
    f32x4 res;
#pragma unroll
    for (int cc = 0; cc < 4; ++cc) {
        float eb = ebias[(sub32 * 4 + cc) * 2 + half];
        res[cc] = gsel[cc] + eb * sa;
    }
    *reinterpret_cast<f32x4*>(orow + half * F + sub32 * 4) = res;
}

// ---------------- dense emb add: out[row][f] += sum_k H[row][k]*W_e[f][k] ----------------
__global__ __launch_bounds__(512) void emb_gemm(const float* __restrict__ H,
                                                const float* __restrict__ W_e,
                                                float* __restrict__ out) {
    __shared__ float WeT[ED][F];
    for (int i = threadIdx.x; i < ED * F; i += 512) {
        int f = i & (F - 1), k = i >> 7;
        WeT[k][f] = W_e[(size_t)f * ED + k];
    }
    __syncthreads();
    int lane = threadIdx.x & 63, wid = threadIdx.x >> 6;
    const int R = NN * C;
    for (int row = blockIdx.x * 8 + wid; row < R; row += gridDim.x * 8) {
        float h = H[(size_t)row * ED + lane];
        float m0 = 0.f, m1 = 0.f;
#pragma unroll
        for (int k = 0; k < ED; ++k) {
            float hk = __shfl(h, k, 64);
            m0 = fmaf(hk, WeT[k][lane], m0);
            m1 = fmaf(hk, WeT[k][lane + 64], m1);
        }
        float* op = out + (size_t)row * F;
        op[lane] += m0;
        op[lane + 64] += m1;
    }
}

extern "C" void kernel_launch(void* const* d_in, const int* in_sizes, int n_in,
                              void* d_out, int out_size, void* d_ws, size_t ws_size,
                              hipStream_t stream) {
    const float* x      = (const float*)d_in[0];
    const int*   ei     = (const int*)d_in[1];
    const float* ea     = (const float*)d_in[2];
    const float* W_l    = (const float*)d_in[3];
    const float* cb     = (const float*)d_in[4];
    const float* att    = (const float*)d_in[5];
    const float* att_sc = (const float*)d_in[6];
    const float* W_e    = (const float*)d_in[7];
    const float* ebias  = (const float*)d_in[8];

    float* out = (float*)d_out;
    float* alpha_out = out + (size_t)NN * C * F;

    float* ws = (float*)d_ws;
    float* xb   = ws;                          // 6,400,000 floats
    float* lgs  = ws + 6400000;                // 1,000,000 floats (original-order logits)
    int* ibase  = (int*)(ws + 7400000);
    int* counts = ibase;                       // NN (becomes cursor)
    int* offs   = ibase + NN;                  // NN+1
    int* bsum   = ibase + 2 * NN + 8;          // 64
    int2* perm2 = (int2*)(ibase + 2 * NN + 128); // NE int2
    float* H    = (float*)(ibase + 2 * NN + 128 + 2 * NE);
    H = (float*)(((size_t)H + 15) & ~(size_t)15);

    hipMemsetAsync(counts, 0, NN * sizeof(int), stream);

    proj_mfma<<<782, 256, 0, stream>>>(x, W_l, xb);

    hist_kernel<<<(NE + 255) / 256, 256, 0, stream>>>(ei, counts);
    const int NB = (NN + 1023) / 1024; // 49
    scan1_kernel<<<NB, 1024, 0, stream>>>(counts, offs, bsum);
    scan2_kernel<<<1, 64, 0, stream>>>(bsum, NB);
    scan3_kernel<<<NB, 1024, 0, stream>>>(offs, bsum, counts); // counts = cursor
    scatter_kernel<<<(NE + 255) / 256, 256, 0, stream>>>(ei, counts, perm2);

    edge_logits_mfma<<<2048, 256, 0, stream>>>(ei, ea, xb, W_e, cb, att,
                                               att_sc, ebias, lgs);

    agg_fast<<<NN / 8, 512, 0, stream>>>(offs, perm2, ea, xb, ebias, lgs,
                                         out, alpha_out, H);

    emb_gemm<<<1024, 512, 0, stream>>>(H, W_e, out);
}

// Round 8
// 466.504 us; speedup vs baseline: 1.0440x; 1.0440x over previous
//
#include <hip/hip_runtime.h>
#include <hip/hip_bf16.h>

#define NN 50000
#define NE 500000
#define F 128
#define K_IN 128
#define ED 64
#define C 2
#define NEG 0.2f
#define FLTMAX 3.402823466e38f

typedef __attribute__((ext_vector_type(8))) short short8;
typedef __attribute__((ext_vector_type(4))) float f32x4;

__device__ __forceinline__ short bf16r(float f) {
    unsigned u = __float_as_uint(f);
    unsigned r = (u + 0x7fffu + ((u >> 16) & 1u)) >> 16;
    return (short)r;
}

__device__ __forceinline__ short8 ldfrag(const float* base) {
    const float4* p = reinterpret_cast<const float4*>(base);
    float4 v0 = p[0], v1 = p[1];
    short8 r;
    r[0] = bf16r(v0.x); r[1] = bf16r(v0.y); r[2] = bf16r(v0.z); r[3] = bf16r(v0.w);
    r[4] = bf16r(v1.x); r[5] = bf16r(v1.y); r[6] = bf16r(v1.z); r[7] = bf16r(v1.w);
    return r;
}

__device__ __forceinline__ float sel4(float a, float b, float c, float d, int j) {
    float r = (j == 1) ? b : a;
    r = (j == 2) ? c : r;
    r = (j == 3) ? d : r;
    return r;
}

// ---------------- projection via MFMA: xb = x @ W_l^T ----------------
__global__ __launch_bounds__(256) void proj_mfma(const float* __restrict__ x,
                                                 const float* __restrict__ W_l,
                                                 float* __restrict__ xb) {
    int lane = threadIdx.x & 63, wid = threadIdx.x >> 6;
    int grp = lane >> 4, col = lane & 15;
    int tile = blockIdx.x * 4 + wid;
    if (tile >= NN / 16) return;
    int n0 = tile * 16;

    f32x4 acc[8];
#pragma unroll
    for (int t = 0; t < 8; ++t) acc[t] = (f32x4){0.f, 0.f, 0.f, 0.f};

    const float* arow = x + (size_t)(n0 + col) * K_IN + grp * 8;
#pragma unroll
    for (int kt = 0; kt < 4; ++kt) {
        short8 a = ldfrag(arow + kt * 32);
#pragma unroll
        for (int t = 0; t < 8; ++t) {
            short8 b = ldfrag(W_l + (size_t)(t * 16 + col) * K_IN + kt * 32 + grp * 8);
            acc[t] = __builtin_amdgcn_mfma_f32_16x16x32_bf16(a, b, acc[t], 0, 0, 0);
        }
    }
#pragma unroll
    for (int j = 0; j < 4; ++j) {
        float* orow = xb + (size_t)(n0 + grp * 4 + j) * F + col;
#pragma unroll
        for (int t = 0; t < 8; ++t) orow[t * 16] = acc[t][j];
    }
}

// ---------------- CSR build ----------------
__global__ void hist_kernel(const int* __restrict__ ei, int* __restrict__ counts) {
    int e = blockIdx.x * blockDim.x + threadIdx.x;
    if (e < NE) atomicAdd(&counts[ei[NE + e]], 1);
}

__global__ __launch_bounds__(1024) void scan1_kernel(const int* __restrict__ counts,
                                                     int* __restrict__ offs,
                                                     int* __restrict__ bsum) {
    __shared__ int wsum[16];
    int i = blockIdx.x * 1024 + threadIdx.x;
    int lane = threadIdx.x & 63, w = threadIdx.x >> 6;
    int v = (i < NN) ? counts[i] : 0;
    int x = v;
#pragma unroll
    for (int off = 1; off < 64; off <<= 1) {
        int y = __shfl_up(x, off, 64);
        if (lane >= off) x += y;
    }
    if (lane == 63) wsum[w] = x;
    __syncthreads();
    if (w == 0 && lane < 16) {
        int t = wsum[lane];
#pragma unroll
        for (int off = 1; off < 16; off <<= 1) {
            int y = __shfl_up(t, off, 16);
            if (lane >= off) t += y;
        }
        wsum[lane] = t;
    }
    __syncthreads();
    int woff = (w == 0) ? 0 : wsum[w - 1];
    if (i < NN) offs[i] = woff + x - v;
    if (threadIdx.x == 1023) bsum[blockIdx.x] = woff + x;
}

__global__ void scan2_kernel(int* __restrict__ bsum, int nb) {
    int tid = threadIdx.x;
    int v = (tid < nb) ? bsum[tid] : 0;
    int x = v;
#pragma unroll
    for (int off = 1; off < 64; off <<= 1) {
        int y = __shfl_up(x, off, 64);
        if (tid >= off) x += y;
    }
    if (tid < nb) bsum[tid] = x - v;
}

__global__ __launch_bounds__(1024) void scan3_kernel(int* __restrict__ offs,
                                                     const int* __restrict__ bsum,
                                                     int* __restrict__ cursor) {
    int i = blockIdx.x * 1024 + threadIdx.x;
    if (i < NN) {
        int o = offs[i] + bsum[blockIdx.x];
        offs[i] = o;
        cursor[i] = o;
    }
    if (i == 0) offs[NN] = NE;
}

// perm2[p] = {edge, src}
__global__ void scatter_kernel(const int* __restrict__ ei, int* __restrict__ cursor,
                               int2* __restrict__ perm2) {
    int e = blockIdx.x * blockDim.x + threadIdx.x;
    if (e < NE) {
        int src = ei[e];
        int p = atomicAdd(&cursor[ei[NE + e]], 1);
        int2 v; v.x = e; v.y = src;
        perm2[p] = v;
    }
}

// ---------------- per-tile logits (16 edges of one node) ----------------
__device__ __forceinline__ void tile_logits(
    int t0, int cnt, const int2* __restrict__ perm2,
    const float* __restrict__ ea, const float* __restrict__ xb,
    const short8 (*Blds)[64], const float* xbt_r,
    const float* attv, const float* cbe0, const float* cbe1,
    float as0, float as1, int lane, int grp, int col,
    float (&q0)[4], float (&q1)[4], int& el, int& sl) {
    int2 pe = perm2[t0 + min(col, cnt - 1)];
    el = pe.x; sl = pe.y;
    const float* arow = ea + (size_t)el * ED + grp * 8;
    short8 a0 = ldfrag(arow);
    short8 a1 = ldfrag(arow + 32);
    f32x4 acc[8];
#pragma unroll
    for (int t = 0; t < 8; ++t) acc[t] = (f32x4){0.f, 0.f, 0.f, 0.f};
#pragma unroll
    for (int t = 0; t < 8; ++t) {
        acc[t] = __builtin_amdgcn_mfma_f32_16x16x32_bf16(a0, Blds[t * 2][lane], acc[t], 0, 0, 0);
        acc[t] = __builtin_amdgcn_mfma_f32_16x16x32_bf16(a1, Blds[t * 2 + 1][lane], acc[t], 0, 0, 0);
    }
#pragma unroll
    for (int j = 0; j < 4; ++j) {
        int idx = grp * 4 + j;
        int src = __shfl(sl, idx, 16);
        const float* xbs = xb + (size_t)src * F + col;
        float a = 0.f, b = 0.f;
#pragma unroll
        for (int t = 0; t < 8; ++t) {
            float s = xbs[t * 16] + xbt_r[t] + acc[t][j];
            float u0 = s + cbe0[t]; u0 = fmaxf(u0, NEG * u0);
            float u1 = s + cbe1[t]; u1 = fmaxf(u1, NEG * u1);
            a = fmaf(u0, attv[t], a);
            b = fmaf(u1, attv[t], b);
        }
#pragma unroll
        for (int off = 1; off < 16; off <<= 1) {
            a += __shfl_xor(a, off, 16);
            b += __shfl_xor(b, off, 16);
        }
        q0[j] = (idx < cnt) ? a * as0 : -FLTMAX;
        q1[j] = (idx < cnt) ? b * as1 : -FLTMAX;
    }
}

// ---------------- fused per-node: logits + online softmax + h/g accumulation ----------------
__global__ __launch_bounds__(256) void fused_node(
    const int* __restrict__ offs, const int2* __restrict__ perm2,
    const float* __restrict__ ea, const float* __restrict__ xb,
    const float* __restrict__ W_e, const float* __restrict__ cb,
    const float* __restrict__ att, const float* __restrict__ att_sc,
    const float* __restrict__ ebias,
    float* __restrict__ out, float* __restrict__ alpha_out,
    float* __restrict__ H) {
    __shared__ short8 Blds[16][64]; // W_e B-fragments, 16 KB
    int lane = threadIdx.x & 63, wid = threadIdx.x >> 6;
    int grp = lane >> 4, col = lane & 15;

    for (int fidx = threadIdx.x; fidx < 1024; fidx += 256) {
        int l = fidx & 63, kt = (fidx >> 6) & 1, t = fidx >> 7;
        int g2 = l >> 4, c2 = l & 15;
        Blds[t * 2 + kt][l] = ldfrag(W_e + (size_t)(t * 16 + c2) * ED + kt * 32 + g2 * 8);
    }
    float attv[8], cbe0[8], cbe1[8];
#pragma unroll
    for (int t = 0; t < 8; ++t) {
        int f = t * 16 + col;
        attv[t] = att[f];
        cbe0[t] = cb[f] + ebias[f * 2];
        cbe1[t] = cb[F + f] + ebias[f * 2 + 1];
    }
    float as0 = att_sc[0], as1 = att_sc[1];
    __syncthreads();

    int node = blockIdx.x * 4 + wid;
    if (node >= NN) return;
    int beg = offs[node], end = offs[node + 1];
    int deg = end - beg;
    float* orow = out + (size_t)node * (C * F);
    float* hrow = H + (size_t)node * (C * ED);
    if (deg == 0) {
        orow[lane] = 0.f; orow[64 + lane] = 0.f;
        orow[128 + lane] = 0.f; orow[192 + lane] = 0.f;
        hrow[lane] = 0.f; hrow[64 + lane] = 0.f;
        return;
    }
    float2* al2 = reinterpret_cast<float2*>(alpha_out);

    // node's own projected row (target side) in registers
    float xbt_r[8];
#pragma unroll
    for (int t = 0; t < 8; ++t) xbt_r[t] = xb[(size_t)node * F + t * 16 + col];

    bool act = lane < deg;
    int el_own = perm2[beg + min(lane, deg - 1)].x;

    float m0 = -FLTMAX, m1 = -FLTMAX, su0 = 0.f, su1 = 0.f;
    float wme0 = 0.f, wme1 = 0.f;
    float h0 = 0.f, h1 = 0.f;                       // k = lane
    float g00 = 0.f, g01 = 0.f, g10 = 0.f, g11 = 0.f; // f = lane / lane+64, per channel

    int ntile = (deg + 15) >> 4;
    for (int tt = 0; tt < ntile; ++tt) {
        int t0 = beg + tt * 16;
        int cnt = min(16, end - t0);
        float q0[4], q1[4]; int el, sl;
        tile_logits(t0, cnt, perm2, ea, xb, Blds, xbt_r, attv, cbe0, cbe1,
                    as0, as1, lane, grp, col, q0, q1, el, sl);

        // tile max per channel (all lanes)
        float tm0 = fmaxf(fmaxf(q0[0], q0[1]), fmaxf(q0[2], q0[3]));
        float tm1 = fmaxf(fmaxf(q1[0], q1[1]), fmaxf(q1[2], q1[3]));
        tm0 = fmaxf(tm0, __shfl_xor(tm0, 16, 64)); tm0 = fmaxf(tm0, __shfl_xor(tm0, 32, 64));
        tm1 = fmaxf(tm1, __shfl_xor(tm1, 16, 64)); tm1 = fmaxf(tm1, __shfl_xor(tm1, 32, 64));
        float nm0 = fmaxf(m0, tm0), nm1 = fmaxf(m1, tm1);
        float sc0 = __expf(m0 - nm0), sc1 = __expf(m1 - nm1);
        su0 *= sc0; su1 *= sc1;
        h0 *= sc0; h1 *= sc1;
        g00 *= sc0; g10 *= sc0; g01 *= sc1; g11 *= sc1;
        wme0 *= sc0; wme1 *= sc1;
        m0 = nm0; m1 = nm1;

        float w0[4], w1[4];
        float ts0 = 0.f, ts1 = 0.f;
#pragma unroll
        for (int j = 0; j < 4; ++j) {
            w0[j] = __expf(q0[j] - m0); w1[j] = __expf(q1[j] - m1);
            ts0 += w0[j]; ts1 += w1[j];
        }
        ts0 += __shfl_xor(ts0, 16, 64); ts0 += __shfl_xor(ts0, 32, 64);
        ts1 += __shfl_xor(ts1, 16, 64); ts1 += __shfl_xor(ts1, 32, 64);
        su0 += ts0; su1 += ts1;

        // capture this lane's own-edge weight (deg<=64 path)
        if (deg <= 64) {
            int idxc = lane & 15, srcl = (idxc >> 2) * 16, jj = idxc & 3;
            float c0a = __shfl(w0[0], srcl, 64), c0b = __shfl(w0[1], srcl, 64);
            float c0c = __shfl(w0[2], srcl, 64), c0d = __shfl(w0[3], srcl, 64);
            float c1a = __shfl(w1[0], srcl, 64), c1b = __shfl(w1[1], srcl, 64);
            float c1c = __shfl(w1[2], srcl, 64), c1d = __shfl(w1[3], srcl, 64);
            float cw0 = sel4(c0a, c0b, c0c, c0d, jj);
            float cw1 = sel4(c1a, c1b, c1c, c1d, jj);
            if ((lane >> 4) == tt) { wme0 = cw0; wme1 = cw1; }
        }

        // accumulate h (k=lane) and g (f=lane/lane+64): rows are L1-hot from frag loads
        for (int i = 0; i < cnt; ++i) {
            int srcl2 = (i >> 2) * 16;
            float d0a = __shfl(w0[0], srcl2, 64), d0b = __shfl(w0[1], srcl2, 64);
            float d0c = __shfl(w0[2], srcl2, 64), d0d = __shfl(w0[3], srcl2, 64);
            float d1a = __shfl(w1[0], srcl2, 64), d1b = __shfl(w1[1], srcl2, 64);
            float d1c = __shfl(w1[2], srcl2, 64), d1d = __shfl(w1[3], srcl2, 64);
            float wi0 = sel4(d0a, d0b, d0c, d0d, i & 3);
            float wi1 = sel4(d1a, d1b, d1c, d1d, i & 3);
            int el_i = __shfl(el, i, 16);
            int src_i = __shfl(sl, i, 16);
            float ev  = ea[(size_t)el_i * ED + lane];
            float xv0 = xb[(size_t)src_i * F + lane];
            float xv1 = xb[(size_t)src_i * F + 64 + lane];
            h0 = fmaf(wi0, ev, h0);   h1 = fmaf(wi1, ev, h1);
            g00 = fmaf(wi0, xv0, g00); g01 = fmaf(wi1, xv0, g01);
            g10 = fmaf(wi0, xv1, g10); g11 = fmaf(wi1, xv1, g11);
        }
    }

    float inv0 = 1.f / (su0 + 1e-16f), inv1 = 1.f / (su1 + 1e-16f);

    if (deg <= 64) {
        if (act) { float2 av; av.x = wme0 * inv0; av.y = wme1 * inv1; al2[el_own] = av; }
    } else {
        // rare: recompute logits per tile and emit alpha directly
        for (int tt = 0; tt < ntile; ++tt) {
            int t0 = beg + tt * 16;
            int cnt = min(16, end - t0);
            float q0[4], q1[4]; int el, sl;
            tile_logits(t0, cnt, perm2, ea, xb, Blds, xbt_r, attv, cbe0, cbe1,
                        as0, as1, lane, grp, col, q0, q1, el, sl);
            float w0[4], w1[4];
#pragma unroll
            for (int j = 0; j < 4; ++j) {
                w0[j] = __expf(q0[j] - m0); w1[j] = __expf(q1[j] - m1);
            }
            int idxc = lane & 15, srcl = (idxc >> 2) * 16, jj = idxc & 3;
            float c0a = __shfl(w0[0], srcl, 64), c0b = __shfl(w0[1], srcl, 64);
            float c0c = __shfl(w0[2], srcl, 64), c0d = __shfl(w0[3], srcl, 64);
            float c1a = __shfl(w1[0], srcl, 64), c1b = __shfl(w1[1], srcl, 64);
            float c1c = __shfl(w1[2], srcl, 64), c1d = __shfl(w1[3], srcl, 64);
            float cw0 = sel4(c0a, c0b, c0c, c0d, jj);
            float cw1 = sel4(c1a, c1b, c1c, c1d, jj);
            if (lane < cnt) { float2 av; av.x = cw0 * inv0; av.y = cw1 * inv1; al2[el] = av; }
        }
    }

    // h rows (normalized) for emb_gemm
    hrow[lane] = h0 * inv0;
    hrow[64 + lane] = h1 * inv1;

    float sa0 = su0 * inv0, sa1 = su1 * inv1;
    float eb00 = ebias[lane * 2];
    float eb01 = ebias[(64 + lane) * 2];
    float eb10 = ebias[lane * 2 + 1];
    float eb11 = ebias[(64 + lane) * 2 + 1];
    orow[lane]       = g00 * inv0 + eb00 * sa0;
    orow[64 + lane]  = g10 * inv0 + eb01 * sa0;
    orow[128 + lane] = g01 * inv1 + eb10 * sa1;
    orow[192 + lane] = g11 * inv1 + eb11 * sa1;
}

// ---------------- dense emb add: out[row][f] += sum_k H[row][k]*W_e[f][k] ----------------
__global__ __launch_bounds__(512) void emb_gemm(const float* __restrict__ H,
                                                const float* __restrict__ W_e,
                                                float* __restrict__ out) {
    __shared__ float WeT[ED][F];
    for (int i = threadIdx.x; i < ED * F; i += 512) {
        int f = i & (F - 1), k = i >> 7;
        WeT[k][f] = W_e[(size_t)f * ED + k];
    }
    __syncthreads();
    int lane = threadIdx.x & 63, wid = threadIdx.x >> 6;
    const int R = NN * C;
    for (int row = blockIdx.x * 8 + wid; row < R; row += gridDim.x * 8) {
        float h = H[(size_t)row * ED + lane];
        float m0 = 0.f, m1 = 0.f;
#pragma unroll
        for (int k = 0; k < ED; ++k) {
            float hk = __shfl(h, k, 64);
            m0 = fmaf(hk, WeT[k][lane], m0);
            m1 = fmaf(hk, WeT[k][lane + 64], m1);
        }
        float* op = out + (size_t)row * F;
        op[lane] += m0;
        op[lane + 64] += m1;
    }
}

extern "C" void kernel_launch(void* const* d_in, const int* in_sizes, int n_in,
                              void* d_out, int out_size, void* d_ws, size_t ws_size,
                              hipStream_t stream) {
    const float* x      = (const float*)d_in[0];
    const int*   ei     = (const int*)d_in[1];
    const float* ea     = (const float*)d_in[2];
    const float* W_l    = (const float*)d_in[3];
    const float* cb     = (const float*)d_in[4];
    const float* att    = (const float*)d_in[5];
    const float* att_sc = (const float*)d_in[6];
    const float* W_e    = (const float*)d_in[7];
    const float* ebias  = (const float*)d_in[8];

    float* out = (float*)d_out;
    float* alpha_out = out + (size_t)NN * C * F;

    float* ws = (float*)d_ws;
    float* xb   = ws;                          // 6,400,000 floats
    int* ibase  = (int*)(ws + 7400000);
    int* counts = ibase;                       // NN (becomes cursor)
    int* offs   = ibase + NN;                  // NN+1
    int* bsum   = ibase + 2 * NN + 8;          // 64
    int2* perm2 = (int2*)(ibase + 2 * NN + 128); // NE int2
    float* H    = (float*)(ibase + 2 * NN + 128 + 2 * NE);
    H = (float*)(((size_t)H + 15) & ~(size_t)15);

    hipMemsetAsync(counts, 0, NN * sizeof(int), stream);

    proj_mfma<<<782, 256, 0, stream>>>(x, W_l, xb);

    hist_kernel<<<(NE + 255) / 256, 256, 0, stream>>>(ei, counts);
    const int NB = (NN + 1023) / 1024; // 49
    scan1_kernel<<<NB, 1024, 0, stream>>>(counts, offs, bsum);
    scan2_kernel<<<1, 64, 0, stream>>>(bsum, NB);
    scan3_kernel<<<NB, 1024, 0, stream>>>(offs, bsum, counts); // counts = cursor
    scatter_kernel<<<(NE + 255) / 256, 256, 0, stream>>>(ei, counts, perm2);

    fused_node<<<(NN + 3) / 4, 256, 0, stream>>>(offs, perm2, ea, xb, W_e, cb,
                                                 att, att_sc, ebias,
                                                 out, alpha_out, H);

    emb_gemm<<<1024, 512, 0, stream>>>(H, W_e, out);
}